// Round 5
// baseline (562.389 us; speedup 1.0000x reference)
//
#include <hip/hip_runtime.h>

// ---------------------------------------------------------------------------
// MetaNet linearized model, MI355X.
//   f0 = xbar @ Wp + bp                      (patch mean is linear)
//   z = f0@W1 + b1 ; f = relu(z) ; base = f@W2 + b2
//   df0 = (c0 (x) xbar)@dWp + sum_t c1 dbp
//   dz  = df0@W1 + (c2 (x) f0)@dW1 + sum_t c3 db1 ; df = mask(z) dz
//   dout= df@W2 + (c4 (x) f)@dW2 + sum_t c5 db2 ; out = base + dout
// GEMMs: A-operand [K,32] wave-uniform (s_load), B streamed coalesced with a
// 32-deep load batch (8KB/wave in flight) pinned by sched_barrier; k-split
// partial buffers (no atomics) + fused reduce kernels.
// ---------------------------------------------------------------------------

__global__ void patch_partial_k(const float* __restrict__ x, float* __restrict__ part) {
    int blk = blockIdx.x;            // b*42 + ch*14 + i   (1344 blocks)
    int i  = blk % 14;
    int ch = (blk / 14) % 3;
    int b  = blk / 42;
    int t  = threadIdx.x;            // py*16 + px
    int py = t >> 4, px = t & 15;
    const float* xp = x + (((size_t)(b*3 + ch))*224 + (size_t)(i*16 + py))*224 + px;
    float s = 0.f;
#pragma unroll
    for (int j = 0; j < 14; ++j) s += xp[j*16];
    part[(size_t)blk*256 + t] = s;
}

__global__ void patch_reduce_k(const float* __restrict__ part, float* __restrict__ xbarT) {
    int idx = blockIdx.x*256 + threadIdx.x;   // 24576 = 32*768
    int b = idx / 768;
    int c = idx % 768;
    int ch = c >> 8, t = c & 255;
    const float* p = part + ((size_t)(b*42 + ch*14))*256 + t;
    float s = 0.f;
#pragma unroll
    for (int i = 0; i < 14; ++i) s += p[i*256];
    xbarT[(size_t)c*32 + b] = s * (1.f/196.f);
}

// P[y][col*32+m] = sum_{k in tile y} AT[k][m] * B[k][col]
// 1 wave/block, 1 col/thread, 32 accumulators. 32 B-loads batched per chunk
// (8KB/wave in flight), batch pinned by sched_barrier(0). launch_bounds
// min-waves=1 so the register allocator keeps all 32 bv live (grid is small;
// occupancy beyond ~2 waves/SIMD is unreachable anyway).
template<int N, int KTILE>
__global__ __launch_bounds__(64, 1) void gemm_k(const float* __restrict__ AT,
                                                const float* __restrict__ Bm,
                                                float* __restrict__ P) {
    int col = blockIdx.x*64 + threadIdx.x;
    size_t k0 = (size_t)blockIdx.y * KTILE;
    float acc[32];
#pragma unroll
    for (int m = 0; m < 32; ++m) acc[m] = 0.f;
    const float* bp = Bm + k0*N + col;
    const float* ap = AT + k0*32;
#pragma unroll 1
    for (int kk = 0; kk < KTILE; kk += 32) {
        float bv[32];
#pragma unroll
        for (int u = 0; u < 32; ++u) bv[u] = bp[(size_t)u*N];
        bp += (size_t)32*N;
        __builtin_amdgcn_sched_barrier(0);   // all 32 loads issued before FMAs
#pragma unroll
        for (int u = 0; u < 32; ++u) {
#pragma unroll
            for (int m = 0; m < 32; ++m) acc[m] += ap[u*32 + m] * bv[u];
        }
        ap += 32*32;
    }
    float* p0 = P + (size_t)blockIdx.y*((size_t)N*32) + (size_t)col*32;
#pragma unroll
    for (int m = 0; m < 32; m += 4)
        *(float4*)(p0 + m) = make_float4(acc[m], acc[m+1], acc[m+2], acc[m+3]);
}

// out[idx] = bias[idx>>5] + sum_y P[y][idx]
template<int Y>
__global__ void reduce_bias_k(const float* __restrict__ P, const float* __restrict__ bias,
                              float* __restrict__ out, int SZ) {
    int idx = blockIdx.x*256 + threadIdx.x;
    float s = bias[idx >> 5];
#pragma unroll
    for (int y = 0; y < Y; ++y) s += P[(size_t)y*SZ + idx];
    out[idx] = s;
}

// z and f=relu(z) in one pass (SZ=98304)
template<int Y>
__global__ void reduce_zf_k(const float* __restrict__ P, const float* __restrict__ bias,
                            float* __restrict__ zT, float* __restrict__ fT) {
    int idx = blockIdx.x*256 + threadIdx.x;
    float s = bias[idx >> 5];
#pragma unroll
    for (int y = 0; y < Y; ++y) s += P[(size_t)y*98304 + idx];
    zT[idx] = s;
    fT[idx] = fmaxf(s, 0.f);
}

// out = init + sum_y P
template<int Y>
__global__ void reduce_arr_k(const float* __restrict__ P, const float* __restrict__ init,
                             float* __restrict__ out, int SZ) {
    int idx = blockIdx.x*256 + threadIdx.x;
    float s = init[idx];
#pragma unroll
    for (int y = 0; y < Y; ++y) s += P[(size_t)y*SZ + idx];
    out[idx] = s;
}

// dfT = (z>0) ? (init + sum_y P) : 0     (SZ=98304)
template<int Y>
__global__ void reduce_mask_k(const float* __restrict__ P, const float* __restrict__ init,
                              const float* __restrict__ zT, float* __restrict__ dfT) {
    int idx = blockIdx.x*256 + threadIdx.x;
    float s = init[idx];
#pragma unroll 16
    for (int y = 0; y < Y; ++y) s += P[(size_t)y*98304 + idx];
    dfT[idx] = zT[idx] > 0.f ? s : 0.f;
}

// out[b,n] = base + init + sum_y P   (un-transpose on store)
template<int Y>
__global__ void reduce_out_k(const float* __restrict__ P, const float* __restrict__ init,
                             const float* __restrict__ baseT, float* __restrict__ out) {
    int idx = blockIdx.x*256 + threadIdx.x;   // 24576
    float s = init[idx] + baseT[idx];
#pragma unroll 16
    for (int y = 0; y < Y; ++y) s += P[(size_t)y*24576 + idx];
    int n = idx >> 5, b = idx & 31;
    out[b*768 + n] = s;
}

// per-sample MetaNet: coefs[b,48] = relu(base[b]@mW1+mb1)@mW2+mb2
__global__ void metanet_k(const float* __restrict__ baseT, const float* __restrict__ mW1,
                          const float* __restrict__ mb1, const float* __restrict__ mW2,
                          const float* __restrict__ mb2, float* __restrict__ coefs) {
    int b = blockIdx.x;           // 32
    int j = threadIdx.x;          // 256
    __shared__ float xb[768];
    __shared__ float v[192];
    for (int i = j; i < 768; i += 256) xb[i] = baseT[(size_t)i*32 + b];
    __syncthreads();
    if (j < 192) {
        float s = mb1[j];
#pragma unroll 8
        for (int i = 0; i < 768; ++i) s += xb[i] * mW1[i*192 + j];
        v[j] = fmaxf(s, 0.f);
    }
    __syncthreads();
    if (j < 48) {
        float s = mb2[j];
#pragma unroll 8
        for (int i = 0; i < 192; ++i) s += v[i] * mW2[i*48 + j];
        coefs[b*48 + j] = s;
    }
}

// G0T/G1T/G2T (coef-scaled A operands) + delta-bias accumulator inits.
__global__ void build_all_k(const float* __restrict__ coefs, const float* __restrict__ xbarT,
                            const float* __restrict__ f0T, const float* __restrict__ fT,
                            const float* __restrict__ dbp, const float* __restrict__ db1,
                            const float* __restrict__ db2,
                            float* __restrict__ G0T, float* __restrict__ G1T,
                            float* __restrict__ G2T, float* __restrict__ df0b,
                            float* __restrict__ dzb, float* __restrict__ doutb) {
    int idx = blockIdx.x*256 + threadIdx.x;   // 1327104 total
    int b = idx & 31;
    int r = idx >> 5;
    if (r < 6144) {
        int t = r / 768, i = r % 768;
        G0T[idx] = coefs[b*48 + t*6 + 0] * xbarT[(size_t)i*32 + b];
    } else if (r < 12288) {
        int rr = r - 6144;
        int t = rr / 768, i = rr % 768;
        G1T[(size_t)rr*32 + b] = coefs[b*48 + t*6 + 2] * f0T[(size_t)i*32 + b];
    } else if (r < 36864) {
        int rr = r - 12288;
        int t = rr / 3072, i = rr % 3072;
        G2T[(size_t)rr*32 + b] = coefs[b*48 + t*6 + 4] * fT[(size_t)i*32 + b];
    } else if (r < 37632) {
        int n = r - 36864;
        float s = 0.f;
#pragma unroll
        for (int t = 0; t < 8; ++t) s += coefs[b*48 + t*6 + 1] * dbp[t*768 + n];
        df0b[(size_t)n*32 + b] = s;
    } else if (r < 40704) {
        int n = r - 37632;
        float s = 0.f;
#pragma unroll
        for (int t = 0; t < 8; ++t) s += coefs[b*48 + t*6 + 3] * db1[t*3072 + n];
        dzb[(size_t)n*32 + b] = s;
    } else if (r < 41472) {
        int n = r - 40704;
        float s = 0.f;
#pragma unroll
        for (int t = 0; t < 8; ++t) s += coefs[b*48 + t*6 + 5] * db2[t*768 + n];
        doutb[(size_t)n*32 + b] = s;
    }
}

extern "C" void kernel_launch(void* const* d_in, const int* in_sizes, int n_in,
                              void* d_out, int out_size, void* d_ws, size_t ws_size,
                              hipStream_t stream) {
    const float* x   = (const float*)d_in[0];
    const float* Wp  = (const float*)d_in[1];
    const float* bp  = (const float*)d_in[2];
    const float* W1  = (const float*)d_in[3];
    const float* b1  = (const float*)d_in[4];
    const float* W2  = (const float*)d_in[5];
    const float* b2  = (const float*)d_in[6];
    const float* dWp = (const float*)d_in[7];
    const float* dbp = (const float*)d_in[8];
    const float* dW1 = (const float*)d_in[9];
    const float* db1 = (const float*)d_in[10];
    const float* dW2 = (const float*)d_in[11];
    const float* db2 = (const float*)d_in[12];
    const float* mW1 = (const float*)d_in[13];
    const float* mb1 = (const float*)d_in[14];
    const float* mW2 = (const float*)d_in[15];
    const float* mb2 = (const float*)d_in[16];
    float* out = (float*)d_out;

    float* ws    = (float*)d_ws;
    float* part  = ws;                 // 344064
    float* xbarT = part  + 344064;     // 24576   [768,32]
    float* f0T   = xbarT + 24576;      // 24576
    float* zT    = f0T   + 24576;      // 98304
    float* fT    = zT    + 98304;      // 98304
    float* baseT = fT    + 98304;      // 24576
    float* coefs = baseT + 24576;      // 1536
    float* G0T   = coefs + 1536;       // 196608  [6144,32]
    float* G1T   = G0T   + 196608;     // 196608  [6144,32]
    float* G2T   = G1T   + 196608;     // 786432  [24576,32]
    float* df0b  = G2T   + 786432;     // 24576
    float* dzb   = df0b  + 24576;      // 98304
    float* doutb = dzb   + 98304;      // 24576
    float* dfT   = doutb + 24576;      // 98304
    float* df0T  = dfT   + 98304;      // 24576
    // partial arenas (reused across phases; no lifetime overlap)
    float* A1 = df0T + 24576;          // 3145728  : Pz (8),  then Pdz (32 slices of 98304)
    float* A2 = A1 + 3145728;          // 3145728  : Pbase(32), then Pdout (128 slices of 24576)
    float* A3 = A2 + 3145728;          // 1179648  : Pf0 (8), then Pdf0 (48 slices of 24576)
    // total ~9.6M floats = ~38.5 MB

    // 1) per-sample patch mean
    patch_partial_k<<<1344, 256, 0, stream>>>(x, part);
    patch_reduce_k<<<96, 256, 0, stream>>>(part, xbarT);

    // 2) base path
    gemm_k<768, 96><<<dim3(12, 8), 64, 0, stream>>>(xbarT, Wp, A3);
    reduce_bias_k<8><<<96, 256, 0, stream>>>(A3, bp, f0T, 24576);
    gemm_k<3072, 96><<<dim3(48, 8), 64, 0, stream>>>(f0T, W1, A1);
    reduce_zf_k<8><<<384, 256, 0, stream>>>(A1, b1, zT, fT);
    gemm_k<768, 96><<<dim3(12, 32), 64, 0, stream>>>(fT, W2, A2);
    reduce_bias_k<32><<<96, 256, 0, stream>>>(A2, b2, baseT, 24576);

    // 3) MetaNet coefficients
    metanet_k<<<32, 256, 0, stream>>>(baseT, mW1, mb1, mW2, mb2, coefs);

    // 4) scaled A-operands + delta-bias inits
    build_all_k<<<5184, 256, 0, stream>>>(coefs, xbarT, f0T, fT, dbp, db1, db2,
                                          G0T, G1T, G2T, df0b, dzb, doutb);

    // 5) JVP chain
    gemm_k<768, 128><<<dim3(12, 48), 64, 0, stream>>>(G0T, dWp, A3);          // 18.9 MB
    reduce_arr_k<48><<<96, 256, 0, stream>>>(A3, df0b, df0T, 24576);
    gemm_k<3072, 96><<<dim3(48, 8), 64, 0, stream>>>(df0T, W1, A1);           // slices 0..8
    gemm_k<3072, 256><<<dim3(48, 24), 64, 0, stream>>>(G1T, dW1, A1 + (size_t)8*98304); // 75.5 MB, 8..32
    reduce_mask_k<32><<<384, 256, 0, stream>>>(A1, dzb, zT, dfT);
    gemm_k<768, 96><<<dim3(12, 32), 64, 0, stream>>>(dfT, W2, A2);            // slices 0..32
    gemm_k<768, 256><<<dim3(12, 96), 64, 0, stream>>>(G2T, dW2, A2 + (size_t)32*24576); // 75.5 MB, 32..128
    reduce_out_k<128><<<96, 256, 0, stream>>>(A2, doutb, baseT, out);
}

// Round 6
// 561.905 us; speedup vs baseline: 1.0009x; 1.0009x over previous
//
#include <hip/hip_runtime.h>

// ---------------------------------------------------------------------------
// MetaNet linearized model, MI355X.
//   f0 = xbar @ Wp + bp                      (patch mean is linear)
//   z = f0@W1 + b1 ; f = relu(z) ; base = f@W2 + b2
//   df0 = (c0 (x) xbar)@dWp + sum_t c1 dbp
//   dz  = df0@W1 + (c2 (x) f0)@dW1 + sum_t c3 db1 ; df = mask(z) dz
//   dout= df@W2 + (c4 (x) f)@dW2 + sum_t c5 db2 ; out = base + dout
// GEMM: 4-wave blocks, each wave owns a KTILE k-subtile (A wave-uniform
// [K,32], B streamed coalesced); LDS cross-wave reduce -> one partial slice
// per block (k-split, no atomics); fused reduce kernels finish each tensor.
// Rationale: per-wave MLP is compiler-pinned at ~1 load in flight (R4/R5),
// so bandwidth must come from wave count: 18 waves/CU on heavy streams.
// ---------------------------------------------------------------------------

__global__ void patch_partial_k(const float* __restrict__ x, float* __restrict__ part) {
    int blk = blockIdx.x;            // b*42 + ch*14 + i   (1344 blocks)
    int i  = blk % 14;
    int ch = (blk / 14) % 3;
    int b  = blk / 42;
    int t  = threadIdx.x;            // py*16 + px
    int py = t >> 4, px = t & 15;
    const float* xp = x + (((size_t)(b*3 + ch))*224 + (size_t)(i*16 + py))*224 + px;
    float s = 0.f;
#pragma unroll
    for (int j = 0; j < 14; ++j) s += xp[j*16];
    part[(size_t)blk*256 + t] = s;
}

__global__ void patch_reduce_k(const float* __restrict__ part, float* __restrict__ xbarT) {
    int idx = blockIdx.x*256 + threadIdx.x;   // 24576 = 32*768
    int b = idx / 768;
    int c = idx % 768;
    int ch = c >> 8, t = c & 255;
    const float* p = part + ((size_t)(b*42 + ch*14))*256 + t;
    float s = 0.f;
#pragma unroll
    for (int i = 0; i < 14; ++i) s += p[i*256];
    xbarT[(size_t)c*32 + b] = s * (1.f/196.f);
}

// P[y][col*32+m] = sum_{k in block tile y} AT[k][m] * B[k][col]
// Block: 256 threads = 4 waves. Wave w handles k-range [y*4*KTILE + w*KTILE).
// Each wave: 64 cols x 32 accumulators. Cross-wave sum via LDS, one slice
// written per block. LDS layout [w][m][lane]: write stride-64 b32 (conflict-
// free), read 4-way (cheap).
template<int N, int KTILE, int CHUNK>
__global__ __launch_bounds__(256) void gemm_k(const float* __restrict__ AT,
                                              const float* __restrict__ Bm,
                                              float* __restrict__ P) {
    __shared__ float red[4*2048];
    int t    = threadIdx.x;
    int lane = t & 63;
    int w    = t >> 6;
    int col  = blockIdx.x*64 + lane;
    size_t k0 = (size_t)blockIdx.y*(4*KTILE) + (size_t)w*KTILE;

    float acc[32];
#pragma unroll
    for (int m = 0; m < 32; ++m) acc[m] = 0.f;
    const float* bp = Bm + k0*N + col;
    const float* ap = AT + k0*32;
#pragma unroll 1
    for (int kk = 0; kk < KTILE; kk += CHUNK) {
        float bv[CHUNK];
#pragma unroll
        for (int u = 0; u < CHUNK; ++u) bv[u] = bp[(size_t)u*N];
        bp += (size_t)CHUNK*N;
        __builtin_amdgcn_sched_barrier(0);   // loads issued before FMA block
#pragma unroll
        for (int u = 0; u < CHUNK; ++u) {
#pragma unroll
            for (int m = 0; m < 32; ++m) acc[m] += ap[u*32 + m] * bv[u];
        }
        ap += CHUNK*32;
    }
    // stash per-wave accumulators: red[w][m][lane]
#pragma unroll
    for (int m = 0; m < 32; ++m) red[w*2048 + m*64 + lane] = acc[m];
    __syncthreads();
    // cross-wave sum; thread t emits 8 consecutive outputs i = t*8..t*8+7,
    // i = col_local*32 + m  (col_local = t/4, m0 = (t*8)&31)
    int col_l = t >> 2;
    int m0 = (t*8) & 31;
    float s[8];
#pragma unroll
    for (int j = 0; j < 8; ++j) s[j] = 0.f;
#pragma unroll
    for (int ww = 0; ww < 4; ++ww)
#pragma unroll
        for (int j = 0; j < 8; ++j) s[j] += red[ww*2048 + (m0+j)*64 + col_l];
    float* p0 = P + (size_t)blockIdx.y*((size_t)N*32) + (size_t)blockIdx.x*2048 + t*8;
    *(float4*)(p0)     = make_float4(s[0], s[1], s[2], s[3]);
    *(float4*)(p0 + 4) = make_float4(s[4], s[5], s[6], s[7]);
}

// out[idx] = bias[idx>>5] + sum_y P[y][idx]
template<int Y>
__global__ void reduce_bias_k(const float* __restrict__ P, const float* __restrict__ bias,
                              float* __restrict__ out, int SZ) {
    int idx = blockIdx.x*256 + threadIdx.x;
    float s = bias[idx >> 5];
#pragma unroll
    for (int y = 0; y < Y; ++y) s += P[(size_t)y*SZ + idx];
    out[idx] = s;
}

// z and f=relu(z) in one pass (SZ=98304)
template<int Y>
__global__ void reduce_zf_k(const float* __restrict__ P, const float* __restrict__ bias,
                            float* __restrict__ zT, float* __restrict__ fT) {
    int idx = blockIdx.x*256 + threadIdx.x;
    float s = bias[idx >> 5];
#pragma unroll
    for (int y = 0; y < Y; ++y) s += P[(size_t)y*98304 + idx];
    zT[idx] = s;
    fT[idx] = fmaxf(s, 0.f);
}

// out = init + sum_y P
template<int Y>
__global__ void reduce_arr_k(const float* __restrict__ P, const float* __restrict__ init,
                             float* __restrict__ out, int SZ) {
    int idx = blockIdx.x*256 + threadIdx.x;
    float s = init[idx];
#pragma unroll
    for (int y = 0; y < Y; ++y) s += P[(size_t)y*SZ + idx];
    out[idx] = s;
}

// dfT = (z>0) ? (init + sum_y P) : 0     (SZ=98304)
template<int Y>
__global__ void reduce_mask_k(const float* __restrict__ P, const float* __restrict__ init,
                              const float* __restrict__ zT, float* __restrict__ dfT) {
    int idx = blockIdx.x*256 + threadIdx.x;
    float s = init[idx];
#pragma unroll 12
    for (int y = 0; y < Y; ++y) s += P[(size_t)y*98304 + idx];
    dfT[idx] = zT[idx] > 0.f ? s : 0.f;
}

// out[b,n] = base + init + sum_y P   (un-transpose on store)
template<int Y>
__global__ void reduce_out_k(const float* __restrict__ P, const float* __restrict__ init,
                             const float* __restrict__ baseT, float* __restrict__ out) {
    int idx = blockIdx.x*256 + threadIdx.x;   // 24576
    float s = init[idx] + baseT[idx];
#pragma unroll 16
    for (int y = 0; y < Y; ++y) s += P[(size_t)y*24576 + idx];
    int n = idx >> 5, b = idx & 31;
    out[b*768 + n] = s;
}

// per-sample MetaNet: coefs[b,48] = relu(base[b]@mW1+mb1)@mW2+mb2
__global__ void metanet_k(const float* __restrict__ baseT, const float* __restrict__ mW1,
                          const float* __restrict__ mb1, const float* __restrict__ mW2,
                          const float* __restrict__ mb2, float* __restrict__ coefs) {
    int b = blockIdx.x;           // 32
    int j = threadIdx.x;          // 256
    __shared__ float xb[768];
    __shared__ float v[192];
    for (int i = j; i < 768; i += 256) xb[i] = baseT[(size_t)i*32 + b];
    __syncthreads();
    if (j < 192) {
        float s = mb1[j];
#pragma unroll 8
        for (int i = 0; i < 768; ++i) s += xb[i] * mW1[i*192 + j];
        v[j] = fmaxf(s, 0.f);
    }
    __syncthreads();
    if (j < 48) {
        float s = mb2[j];
#pragma unroll 8
        for (int i = 0; i < 192; ++i) s += v[i] * mW2[i*48 + j];
        coefs[b*48 + j] = s;
    }
}

// G0T/G1T/G2T (coef-scaled A operands) + delta-bias accumulator inits.
__global__ void build_all_k(const float* __restrict__ coefs, const float* __restrict__ xbarT,
                            const float* __restrict__ f0T, const float* __restrict__ fT,
                            const float* __restrict__ dbp, const float* __restrict__ db1,
                            const float* __restrict__ db2,
                            float* __restrict__ G0T, float* __restrict__ G1T,
                            float* __restrict__ G2T, float* __restrict__ df0b,
                            float* __restrict__ dzb, float* __restrict__ doutb) {
    int idx = blockIdx.x*256 + threadIdx.x;   // 1327104 total
    int b = idx & 31;
    int r = idx >> 5;
    if (r < 6144) {
        int t = r / 768, i = r % 768;
        G0T[idx] = coefs[b*48 + t*6 + 0] * xbarT[(size_t)i*32 + b];
    } else if (r < 12288) {
        int rr = r - 6144;
        int t = rr / 768, i = rr % 768;
        G1T[(size_t)rr*32 + b] = coefs[b*48 + t*6 + 2] * f0T[(size_t)i*32 + b];
    } else if (r < 36864) {
        int rr = r - 12288;
        int t = rr / 3072, i = rr % 3072;
        G2T[(size_t)rr*32 + b] = coefs[b*48 + t*6 + 4] * fT[(size_t)i*32 + b];
    } else if (r < 37632) {
        int n = r - 36864;
        float s = 0.f;
#pragma unroll
        for (int t = 0; t < 8; ++t) s += coefs[b*48 + t*6 + 1] * dbp[t*768 + n];
        df0b[(size_t)n*32 + b] = s;
    } else if (r < 40704) {
        int n = r - 37632;
        float s = 0.f;
#pragma unroll
        for (int t = 0; t < 8; ++t) s += coefs[b*48 + t*6 + 3] * db1[t*3072 + n];
        dzb[(size_t)n*32 + b] = s;
    } else if (r < 41472) {
        int n = r - 40704;
        float s = 0.f;
#pragma unroll
        for (int t = 0; t < 8; ++t) s += coefs[b*48 + t*6 + 5] * db2[t*768 + n];
        doutb[(size_t)n*32 + b] = s;
    }
}

extern "C" void kernel_launch(void* const* d_in, const int* in_sizes, int n_in,
                              void* d_out, int out_size, void* d_ws, size_t ws_size,
                              hipStream_t stream) {
    const float* x   = (const float*)d_in[0];
    const float* Wp  = (const float*)d_in[1];
    const float* bp  = (const float*)d_in[2];
    const float* W1  = (const float*)d_in[3];
    const float* b1  = (const float*)d_in[4];
    const float* W2  = (const float*)d_in[5];
    const float* b2  = (const float*)d_in[6];
    const float* dWp = (const float*)d_in[7];
    const float* dbp = (const float*)d_in[8];
    const float* dW1 = (const float*)d_in[9];
    const float* db1 = (const float*)d_in[10];
    const float* dW2 = (const float*)d_in[11];
    const float* db2 = (const float*)d_in[12];
    const float* mW1 = (const float*)d_in[13];
    const float* mb1 = (const float*)d_in[14];
    const float* mW2 = (const float*)d_in[15];
    const float* mb2 = (const float*)d_in[16];
    float* out = (float*)d_out;

    float* ws    = (float*)d_ws;
    float* part  = ws;                 // 344064
    float* xbarT = part  + 344064;     // 24576   [768,32]
    float* f0T   = xbarT + 24576;      // 24576
    float* zT    = f0T   + 24576;      // 98304
    float* fT    = zT    + 98304;      // 98304
    float* baseT = fT    + 98304;      // 24576
    float* coefs = baseT + 24576;      // 1536
    float* G0T   = coefs + 1536;       // 196608  [6144,32]
    float* G1T   = G0T   + 196608;     // 196608  [6144,32]
    float* G2T   = G1T   + 196608;     // 786432  [24576,32]
    float* df0b  = G2T   + 786432;     // 24576
    float* dzb   = df0b  + 24576;      // 98304
    float* doutb = dzb   + 98304;      // 24576
    float* dfT   = doutb + 24576;      // 98304
    float* df0T  = dfT   + 98304;      // 24576
    // partial arenas (reused across phases; no lifetime overlap)
    float* A1 = df0T + 24576;          // 3538944 : Pz (12 x 98304), then Pdz (36 x 98304)
    float* A2 = A1 + 3538944;          // 3538944 : Pbase (48 x 24576), then Pdout (144 x 24576)
    float* A3 = A2 + 3538944;          // 1179648 : Pf0 (24 x 24576), then Pdf0 (48 x 24576)
    // total ~10.1M floats = ~40.5 MB

    // 1) per-sample patch mean
    patch_partial_k<<<1344, 256, 0, stream>>>(x, part);
    patch_reduce_k<<<96, 256, 0, stream>>>(part, xbarT);

    // 2) base path
    gemm_k<768, 8, 8><<<dim3(12, 24), 256, 0, stream>>>(xbarT, Wp, A3);      // K=768, 1152 waves
    reduce_bias_k<24><<<96, 256, 0, stream>>>(A3, bp, f0T, 24576);
    gemm_k<3072, 16, 16><<<dim3(48, 12), 256, 0, stream>>>(f0T, W1, A1);     // K=768, 2304 waves
    reduce_zf_k<12><<<384, 256, 0, stream>>>(A1, b1, zT, fT);
    gemm_k<768, 16, 16><<<dim3(12, 48), 256, 0, stream>>>(fT, W2, A2);       // K=3072, 2304 waves
    reduce_bias_k<48><<<96, 256, 0, stream>>>(A2, b2, baseT, 24576);

    // 3) MetaNet coefficients
    metanet_k<<<32, 256, 0, stream>>>(baseT, mW1, mb1, mW2, mb2, coefs);

    // 4) scaled A-operands + delta-bias inits
    build_all_k<<<5184, 256, 0, stream>>>(coefs, xbarT, f0T, fT, dbp, db1, db2,
                                          G0T, G1T, G2T, df0b, dzb, doutb);

    // 5) JVP chain (heavy streams: dWp 18.9MB, dW1 75.5MB, dW2 75.5MB)
    gemm_k<768, 32, 32><<<dim3(12, 48), 256, 0, stream>>>(G0T, dWp, A3);     // K=6144, 2304 waves
    reduce_arr_k<48><<<96, 256, 0, stream>>>(A3, df0b, df0T, 24576);
    gemm_k<3072, 16, 16><<<dim3(48, 12), 256, 0, stream>>>(df0T, W1, A1);    // slices 0..12
    gemm_k<3072, 64, 32><<<dim3(48, 24), 256, 0, stream>>>(G1T, dW1, A1 + (size_t)12*98304); // 12..36, 4608 waves
    reduce_mask_k<36><<<384, 256, 0, stream>>>(A1, dzb, zT, dfT);
    gemm_k<768, 16, 16><<<dim3(12, 48), 256, 0, stream>>>(dfT, W2, A2);      // slices 0..48
    gemm_k<768, 64, 32><<<dim3(12, 96), 256, 0, stream>>>(G2T, dW2, A2 + (size_t)48*24576); // 48..144, 4608 waves
    reduce_out_k<144><<<96, 256, 0, stream>>>(A2, doutb, baseT, out);
}